// Round 8
// baseline (838.392 us; speedup 1.0000x reference)
//
#include <hip/hip_runtime.h>

// ---------------------------------------------------------------------------
// ConvLinformerSelfAttention (MI355X/gfx950) — bf16 MFMA pipeline, round 8.
// conv v7: A (Wr) fragments global->VGPR (reg dbuf, one step ahead);
//          only Kt in LDS (20 KB, gld16 DMA, dbuf). 512 thr, 8 waves 4Mx2N,
//          grid 512 = 2 blocks/CU (16 waves/CU). qk stays v4, out stays v3.
// ---------------------------------------------------------------------------

typedef short v8s __attribute__((ext_vector_type(8)));   // 8 x bf16 bits
typedef float v4f __attribute__((ext_vector_type(4)));

#define MFMA16(a, b, c) __builtin_amdgcn_mfma_f32_16x16x32_bf16((a), (b), (c), 0, 0, 0)
#define WAITV(N) asm volatile("s_waitcnt vmcnt(" #N ")" ::: "memory")
#define SBAR() __builtin_amdgcn_s_barrier()

__device__ __forceinline__ unsigned short f2bf(float f) {
  unsigned int u = __float_as_uint(f);
  u += 0x7fffu + ((u >> 16) & 1u);   // RNE
  return (unsigned short)(u >> 16);
}

__device__ __forceinline__ v8s cvt8(float4 a, float4 b) {
  v8s v;
  v[0] = (short)f2bf(a.x); v[1] = (short)f2bf(a.y);
  v[2] = (short)f2bf(a.z); v[3] = (short)f2bf(a.w);
  v[4] = (short)f2bf(b.x); v[5] = (short)f2bf(b.y);
  v[6] = (short)f2bf(b.z); v[7] = (short)f2bf(b.w);
  return v;
}

// async global->LDS, 16B per lane; LDS dest = uniform base + lane*16.
__device__ __forceinline__ void gld16(void* lds, const void* g) {
  __builtin_amdgcn_global_load_lds(
      (const __attribute__((address_space(1))) void*)g,
      (__attribute__((address_space(3))) void*)lds, 16, 0, 0);
}

// Fragment pointer into a swizzled [rows][32] bf16 LDS tile.
// Storage: LDS(row, seg') holds global seg = seg' ^ ((row>>1)&3).
__device__ __forceinline__ const v8s* frag_ptr(const short* base, int row, int g) {
  return (const v8s*)(base + row * 32 + (((g ^ (row >> 1)) & 3) << 3));
}

// --------------------------------------------------------------- cvt f32->bf16
__global__ __launch_bounds__(256) void k_cvt(const float* __restrict__ src,
                                             short* __restrict__ dst, int n8) {
  const int i = blockIdx.x * 256 + threadIdx.x;
  if (i >= n8) return;
  const float4* s = (const float4*)src;
  ((v8s*)dst)[i] = cvt8(s[2 * i], s[2 * i + 1]);
}

// --------------------------------------------------------------- reorder Wpk
__global__ __launch_bounds__(256) void k_reorder_wpk(const float* __restrict__ Wpk,
                                                     short* __restrict__ Wr) {
  __shared__ short T[64][40];
  const int k  = blockIdx.x >> 6;
  const int n0 = (blockIdx.x & 63) << 6;
  const int tid = threadIdx.x;
  {
    const int i = tid >> 2, t0 = (tid & 3) << 3;
    const float* p = Wpk + ((size_t)k * 4096 + n0 + i) * 32 + t0;
    float4 a = *(const float4*)p, b = *(const float4*)(p + 4);
    *(v8s*)&T[i][t0] = cvt8(a, b);
  }
  __syncthreads();
  {
    const int t = tid >> 3, j0 = (tid & 7) << 3;
    v8s o;
#pragma unroll
    for (int q = 0; q < 8; ++q) o[q] = T[j0 + q][t];
    *(v8s*)(Wr + ((size_t)t * 256 + k) * 4096 + n0 + j0) = o;
  }
}

// --------------------------------------------------------------- zero pads
__global__ __launch_bounds__(256) void k_zero_pad(short* __restrict__ KpTp) {
  const int idx = blockIdx.x * 256 + threadIdx.x;   // < 65536
  const int ridx = idx >> 9, col8 = idx & 511;
  const int b = ridx >> 5, rr = ridx & 31;
  const int row = (rr < 15) ? rr : 1039 + (rr - 15);
  v8s z = {0, 0, 0, 0, 0, 0, 0, 0};
  *(v8s*)(KpTp + ((size_t)b * 1056 + row) * 4096 + col8 * 8) = z;
}

// --------------------------------------------------------------- QK GEMM v4
// [Q|Kp](16384x2048) = xbf @ Wqk^T. grid (64,16): block 256(M)x128(N),
// 4 waves of 64x128, depth-1 counted vmcnt.
__global__ __launch_bounds__(256, 2) void k_gemm_qk_v4(const short* __restrict__ xbf,
                                                       const short* __restrict__ Wqk,
                                                       short* __restrict__ Qbf,
                                                       short* __restrict__ Kp) {
  __shared__ short As[2][256][32];
  __shared__ short Bs[2][128][32];
  const int tid = threadIdx.x, lane = tid & 63, w = tid >> 6;
  const int m0 = blockIdx.x * 256, j0 = blockIdx.y * 128;
  const int wm = w * 64;
  const int l15 = lane & 15, g = lane >> 4;
  const int lr = lane >> 2, lseg = lane & 3;

  v4f acc[4][8];
#pragma unroll
  for (int i = 0; i < 4; ++i)
#pragma unroll
    for (int j = 0; j < 8; ++j) acc[i][j] = (v4f)0.0f;

  auto stage = [&](int buf, int k0) {
#pragma unroll
    for (int q = 0; q < 4; ++q) {                 // A: 256 rows, 4 rounds
      const int rblk = q * 64 + w * 16, r = rblk + lr;
      const int co = ((lseg ^ (r >> 1)) & 3) << 3;
      gld16(&As[buf][rblk][0], xbf + (size_t)(m0 + r) * 1024 + k0 + co);
    }
#pragma unroll
    for (int q = 0; q < 2; ++q) {                 // B: 128 rows, 2 rounds
      const int rblk = q * 64 + w * 16, r = rblk + lr;
      const int co = ((lseg ^ (r >> 1)) & 3) << 3;
      gld16(&Bs[buf][rblk][0], Wqk + (size_t)(j0 + r) * 1024 + k0 + co);
    }
  };

  stage(0, 0);
#pragma unroll 1
  for (int p = 0, buf = 0; p < 32; ++p, buf ^= 1) {
    if (p + 1 < 32) stage(buf ^ 1, (p + 1) * 32);
    if (p < 31) { WAITV(6); } else { WAITV(0); }
    SBAR();
    v8s af[4];
#pragma unroll
    for (int mi = 0; mi < 4; ++mi)
      af[mi] = *frag_ptr(&As[buf][0][0], wm + mi * 16 + l15, g);
    __builtin_amdgcn_s_setprio(1);
#pragma unroll
    for (int nh = 0; nh < 2; ++nh) {
      v8s bq[4];
#pragma unroll
      for (int nj = 0; nj < 4; ++nj)
        bq[nj] = *frag_ptr(&Bs[buf][0][0], nh * 64 + nj * 16 + l15, g);
#pragma unroll
      for (int nj = 0; nj < 4; ++nj)
#pragma unroll
        for (int mi = 0; mi < 4; ++mi)
          acc[mi][nh * 4 + nj] = MFMA16(af[mi], bq[nj], acc[mi][nh * 4 + nj]);
    }
    __builtin_amdgcn_s_setprio(0);
    SBAR();
  }
  const int rbase = g * 4;
#pragma unroll
  for (int mi = 0; mi < 4; ++mi)
#pragma unroll
    for (int nf = 0; nf < 8; ++nf) {
      const int col = j0 + nf * 16 + l15;
      short* dst = (col < 1024) ? Qbf : Kp;
      const int cj = (col < 1024) ? col : col - 1024;
#pragma unroll
      for (int r = 0; r < 4; ++r) {
        const int row = m0 + wm + mi * 16 + rbase + r;
        dst[(size_t)row * 1024 + cj] = (short)f2bf(acc[mi][nf][r]);
      }
    }
}

// --------------------------------------------------------------- transpose+pad
__global__ __launch_bounds__(256) void k_transpose_pad(const short* __restrict__ src,
                                                       short* __restrict__ dst) {
  __shared__ short T[64][72];
  const int r0 = blockIdx.x * 64, c0 = blockIdx.y * 64, b = blockIdx.z;
  const int tid = threadIdx.x;
  {
    const int i = tid >> 2, q = (tid & 3) << 4;
    const short* ps = src + ((size_t)b * 4096 + r0 + i) * 1024 + c0 + q;
    *(v8s*)&T[i][q]     = *(const v8s*)ps;
    *(v8s*)&T[i][q + 8] = *(const v8s*)(ps + 8);
  }
  __syncthreads();
  {
    const int j = tid >> 2, p = (tid & 3) << 4;
    v8s o0, o1;
#pragma unroll
    for (int t = 0; t < 8; ++t) o0[t] = T[p + t][j];
#pragma unroll
    for (int t = 0; t < 8; ++t) o1[t] = T[p + 8 + t][j];
    short* pd = dst + ((size_t)b * 1056 + 15 + c0 + j) * 4096 + r0 + p;
    *(v8s*)pd = o0;
    *(v8s*)(pd + 8) = o1;
  }
}

// --------------------------------------------------------------- conv GEMM v7
// P[ns][b][kch 256][d-window 128] = sum_{t,n in ns-chunk} Wr x shifted(KpTp)
// grid 512 = ns(16) x b(4) x nt(8); 512 thr, 8 waves 4Mx2N of 64x64.
// A fragments: global->VGPR, reg-dbuf 1 step ahead (compiler-scored vmcnt).
// B (Kt): LDS dbuf via gld16; manual WAITV(4)@t==31 + SBAR covers DMA.
__global__ __launch_bounds__(512, 4) void k_conv_v7(const short* __restrict__ Wr,
                                                    const short* __restrict__ KpTp,
                                                    float* __restrict__ Pq) {
  __shared__ short Kt[2][160][32];   // 20 KB: halo'd KpTp (159 used rows), dbuf
  const int bid = blockIdx.x;
  // 32 blocks sharing one A-stream (same ns) share bid%8 -> same XCD L2.
  const int ns = (bid & 7) | (((bid >> 8) & 1) << 3);
  const int j  = (bid >> 3) & 31;
  const int b = j >> 3, nt = j & 7;
  const int D0 = nt * 128;
  const int nbase = ns * 256;
  const int tid = threadIdx.x, lane = tid & 63, w = tid >> 6;
  const int wm = (w >> 1) * 64, wn = (w & 1) * 64;
  const int l15 = lane & 15, g = lane >> 4;
  const int lr = lane >> 2, lseg = lane & 3;
  const short* KpTb = KpTp + (size_t)b * 1056 * 4096;

  v4f acc[4][4];
#pragma unroll
  for (int mi = 0; mi < 4; ++mi)
#pragma unroll
    for (int ni = 0; ni < 4; ++ni) acc[mi][ni] = (v4f)0.0f;

  // A fragment load for step s, sub-tile mi: 16B per lane from Wr.
  // Lane row = wm + mi*16 + l15 (fixed); col block = c*32 + g*8.
  const short* Abase = Wr + (size_t)(wm + l15) * 4096 + nbase + g * 8;
  auto ldA = [&](int s, int mi) -> v8s {
    const int t = s & 31, c = s >> 5;
    return *(const v8s*)(Abase + ((size_t)t * 256 + mi * 16) * 4096 + c * 32);
  };
  // Kt staging: 10 rounds of 16 rows; 2 issues/lane wave-uniform
  // (waves 2-7 duplicate their first round with identical bytes).
  auto stageKt = [&](int buf, int c1) {
    const int q1 = w, q2 = (w < 2) ? 8 + w : w;
#pragma unroll
    for (int pass = 0; pass < 2; ++pass) {
      const int q = pass ? q2 : q1;
      const int rblk = q * 16, row = rblk + lr;
      const int srow = row < 159 ? row : 158;
      const int sg = ((lseg ^ (row >> 1)) & 3) << 3;
      gld16(&Kt[buf][rblk][0],
            KpTb + (size_t)(D0 + srow) * 4096 + nbase + c1 * 32 + sg);
    }
  };

  // prologue: Kt(0) DMA + af(0) regs; drain all, barrier.
  stageKt(0, 0);
  v8s afc[4], afn[4];
#pragma unroll
  for (int mi = 0; mi < 4; ++mi) afc[mi] = ldA(0, mi);
  WAITV(0);
  SBAR();

#pragma unroll 1
  for (int s = 0; s < 256; ++s) {
    const int t = s & 31, c = s >> 5;
    if (s + 1 < 256) {
#pragma unroll
      for (int mi = 0; mi < 4; ++mi) afn[mi] = ldA(s + 1, mi);
    }
    if (t == 26 && c < 7) stageKt((c + 1) & 1, c + 1);
    const short* Ktp = &Kt[c & 1][0][0];
    v8s bq[4];
#pragma unroll
    for (int nj = 0; nj < 4; ++nj)
      bq[nj] = *frag_ptr(Ktp, wn + nj * 16 + l15 + t, g);
    __builtin_amdgcn_s_setprio(1);
#pragma unroll
    for (int ni = 0; ni < 4; ++ni)
#pragma unroll
      for (int mi = 0; mi < 4; ++mi)
        acc[mi][ni] = MFMA16(afc[mi], bq[ni], acc[mi][ni]);
    __builtin_amdgcn_s_setprio(0);
    // chunk boundary: ensure this wave's Kt DMA (issued t==26) retired
    // before any wave ds_reads the new buffer after the barrier. Keeps
    // the 4 af(s+1) loads (newest) in flight.
    if (t == 31) { WAITV(4); }
    SBAR();
#pragma unroll
    for (int mi = 0; mi < 4; ++mi) afc[mi] = afn[mi];
  }

  float* Pp = Pq + (size_t)(ns * 4 + b) * 262144;  // [256][1024] window
#pragma unroll
  for (int mi = 0; mi < 4; ++mi)
#pragma unroll
    for (int ni = 0; ni < 4; ++ni) {
      const int col = D0 + wn + ni * 16 + l15;
#pragma unroll
      for (int r = 0; r < 4; ++r)
        Pp[(size_t)(wm + mi * 16 + g * 4 + r) * 1024 + col] = acc[mi][ni][r];
    }
}

// --------------------------------------------------------------- reduce Kc
// Kc[i] = bpk[k] + sum_{ns<16} P[ns][i], i over (4,256,1024). grid 1024x256.
__global__ __launch_bounds__(256) void k_reduce_kc(const float* __restrict__ P,
                                                   const float* __restrict__ bpk,
                                                   float* __restrict__ Kc) {
  const int i = (blockIdx.x * 256 + threadIdx.x) * 4;  // < 4*256*1024
  const float bias = bpk[(i >> 10) & 255];
  float4 s; s.x = bias; s.y = bias; s.z = bias; s.w = bias;
#pragma unroll
  for (int ns = 0; ns < 16; ++ns) {
    float4 v = *(const float4*)(P + (size_t)ns * 1048576 + i);
    s.x += v.x; s.y += v.y; s.z += v.z; s.w += v.w;
  }
  *(float4*)(Kc + i) = s;
}

// --------------------------------------------------------------- Kc post
__global__ __launch_bounds__(256) void k_kc_post(const float* __restrict__ Kc,
                                                 short* __restrict__ Kcbf,
                                                 short* __restrict__ KcT) {
  __shared__ short T[64][72];
  const int k0 = blockIdx.x * 64, d0 = blockIdx.y * 64, b = blockIdx.z;
  const int tid = threadIdx.x;
  {
    const int i = tid >> 2, q = (tid & 3) << 4;
    const float* ps = Kc + (size_t)(b * 256 + k0 + i) * 1024 + d0 + q;
    float4 f0 = *(const float4*)ps,       f1 = *(const float4*)(ps + 4);
    float4 f2 = *(const float4*)(ps + 8), f3 = *(const float4*)(ps + 12);
    v8s v0 = cvt8(f0, f1), v1 = cvt8(f2, f3);
    *(v8s*)&T[i][q] = v0;
    *(v8s*)&T[i][q + 8] = v1;
    short* pc = Kcbf + (size_t)(b * 256 + k0 + i) * 1024 + d0 + q;
    *(v8s*)pc = v0;
    *(v8s*)(pc + 8) = v1;
  }
  __syncthreads();
  {
    const int j = tid >> 2, p = (tid & 3) << 4;
    v8s o0, o1;
#pragma unroll
    for (int t = 0; t < 8; ++t) o0[t] = T[p + t][j];
#pragma unroll
    for (int t = 0; t < 8; ++t) o1[t] = T[p + 8 + t][j];
    short* pd = KcT + (size_t)(b * 1024 + d0 + j) * 256 + k0 + p;
    *(v8s*)pd = o0;
    *(v8s*)(pd + 8) = o1;
  }
}

// --------------------------------------------------------------- attention
__global__ __launch_bounds__(256) void k_attn(const short* __restrict__ Qbf,
                                              const short* __restrict__ Kcbf,
                                              const short* __restrict__ KcT,
                                              short* __restrict__ AO) {
  __shared__ short P[4][16][264];
  const int nt = blockIdx.x, h = blockIdx.y, b = blockIdx.z;
  const int tid = threadIdx.x, lane = tid & 63, w = tid >> 6;
  const int l15 = lane & 15, lg4 = (lane >> 4) * 4, lg8 = (lane >> 4) * 8;
  const float scale = 0.08838834764831845f;
  const size_t qb  = (size_t)b * 4096 * 1024 + (size_t)h * 128;
  const size_t kb  = (size_t)b * 256 * 1024 + (size_t)h * 128;
  const size_t vtb = ((size_t)b * 1024 + (size_t)h * 128) * 256;
  short (*Pw)[264] = P[w];
  const int n_wave = nt * 128 + w * 32;

#pragma unroll 1
  for (int half = 0; half < 2; ++half) {
    const int nbase = n_wave + half * 16;
    v8s aq[4];
#pragma unroll
    for (int kt = 0; kt < 4; ++kt)
      aq[kt] = *(const v8s*)(Qbf + qb + (size_t)(nbase + l15) * 1024 + kt * 32 + lg8);

    v4f dacc[16];
#pragma unroll
    for (int ct = 0; ct < 16; ++ct) dacc[ct] = (v4f)0.0f;
#pragma unroll 1
    for (int kt = 0; kt < 4; ++kt) {
#pragma unroll
      for (int ct = 0; ct < 16; ++ct) {
        v8s bk = *(const v8s*)(Kcbf + kb + (size_t)(ct * 16 + l15) * 1024 + kt * 32 + lg8);
        dacc[ct] = MFMA16(aq[kt], bk, dacc[ct]);
      }
    }
#pragma unroll
    for (int ct = 0; ct < 16; ++ct) dacc[ct] = dacc[ct] * scale;
    v4f m4 = dacc[0];
#pragma unroll
    for (int ct = 1; ct < 16; ++ct)
#pragma unroll
      for (int r = 0; r < 4; ++r) m4[r] = fmaxf(m4[r], dacc[ct][r]);
#pragma unroll
    for (int off = 1; off < 16; off <<= 1)
#pragma unroll
      for (int r = 0; r < 4; ++r) m4[r] = fmaxf(m4[r], __shfl_xor(m4[r], off, 64));
    v4f ssum = (v4f)0.0f;
#pragma unroll
    for (int ct = 0; ct < 16; ++ct)
#pragma unroll
      for (int r = 0; r < 4; ++r) {
        const float e = __expf(dacc[ct][r] - m4[r]);
        ssum[r] += e;
        Pw[lg4 + r][ct * 16 + l15] = (short)f2bf(e);
      }
#pragma unroll
    for (int off = 1; off < 16; off <<= 1)
#pragma unroll
      for (int r = 0; r < 4; ++r) ssum[r] += __shfl_xor(ssum[r], off, 64);
    __syncthreads();

    v4f oacc[8];
#pragma unroll
    for (int ct = 0; ct < 8; ++ct) oacc[ct] = (v4f)0.0f;
#pragma unroll 1
    for (int kt2 = 0; kt2 < 8; ++kt2) {
      v8s pa = *(const v8s*)&Pw[l15][kt2 * 32 + lg8];
#pragma unroll
      for (int ct = 0; ct < 8; ++ct) {
        v8s bv = *(const v8s*)(KcT + vtb + (size_t)(ct * 16 + l15) * 256 + kt2 * 32 + lg8);
        oacc[ct] = MFMA16(pa, bv, oacc[ct]);
      }
    }
    v4f inv;
#pragma unroll
    for (int r = 0; r < 4; ++r) inv[r] = 1.0f / ssum[r];
#pragma unroll
    for (int ct = 0; ct < 8; ++ct)
#pragma unroll
      for (int r = 0; r < 4; ++r)
        AO[qb + (size_t)(nbase + lg4 + r) * 1024 + ct * 16 + l15] =
            (short)f2bf(oacc[ct][r] * inv[r]);
    __syncthreads();
  }
}

// --------------------------------------------------------------- out GEMM v3 (control)
__global__ __launch_bounds__(256) void k_gemm_out_v3(const short* __restrict__ AO,
                                                     const short* __restrict__ Wobf,
                                                     const float* __restrict__ bo,
                                                     float* __restrict__ out) {
  __shared__ short As[2][128][32];
  __shared__ short Bs[2][128][32];
  const int tid = threadIdx.x, lane = tid & 63, w = tid >> 6;
  const int m0 = blockIdx.x * 128, j0 = blockIdx.y * 128;
  const int wr = (w >> 1) * 64, wc = (w & 1) * 64;
  const int l15 = lane & 15, g = lane >> 4;
  const int sr = lane >> 2, sseg = lane & 3;

  v4f acc[4][4];
#pragma unroll
  for (int i = 0; i < 4; ++i)
#pragma unroll
    for (int j = 0; j < 4; ++j) acc[i][j] = (v4f)0.0f;

  auto stage = [&](int buf, int k0) {
#pragma unroll
    for (int q0 = 0; q0 < 2; ++q0) {
      const int rblk = (w * 2 + q0) << 4, r = rblk + sr;
      const int co = ((sseg ^ (r >> 1)) & 3) << 3;
      gld16(&As[buf][rblk][0], AO + (size_t)(m0 + r) * 1024 + k0 + co);
      gld16(&Bs[buf][rblk][0], Wobf + (size_t)(j0 + r) * 1024 + k0 + co);
    }
  };

  stage(0, 0);
#pragma unroll 1
  for (int p = 0, buf = 0; p < 32; ++p, buf ^= 1) {
    if (p + 1 < 32) stage(buf ^ 1, (p + 1) * 32);
    if (p < 31) { WAITV(4); } else { WAITV(0); }
    SBAR();
    v8s af[4], bf4[4];
#pragma unroll
    for (int mi = 0; mi < 4; ++mi)
      af[mi] = *frag_ptr(&As[buf][0][0], wr + mi * 16 + l15, g);
#pragma unroll
    for (int ni = 0; ni < 4; ++ni)
      bf4[ni] = *frag_ptr(&Bs[buf][0][0], wc + ni * 16 + l15, g);
#pragma unroll
    for (int ni = 0; ni < 4; ++ni)
#pragma unroll
      for (int mi = 0; mi < 4; ++mi)
        acc[mi][ni] = MFMA16(af[mi], bf4[ni], acc[mi][ni]);
    SBAR();
  }
  const int rbase = (lane >> 4) * 4;
#pragma unroll
  for (int mi = 0; mi < 4; ++mi)
#pragma unroll
    for (int ni = 0; ni < 4; ++ni) {
      const int col = j0 + wc + ni * 16 + l15;
      const float bias = bo[col];
#pragma unroll
      for (int r = 0; r < 4; ++r) {
        const int row = m0 + wr + mi * 16 + rbase + r;
        out[(size_t)row * 1024 + col] = acc[mi][ni][r] + bias;
      }
    }
}

// ---------------------------------------------------------------------------
extern "C" void kernel_launch(void* const* d_in, const int* in_sizes, int n_in,
                              void* d_out, int out_size, void* d_ws, size_t ws_size,
                              hipStream_t stream) {
  const float* x   = (const float*)d_in[0];
  const float* Wq  = (const float*)d_in[1];
  const float* Wk  = (const float*)d_in[2];
  const float* Wpk = (const float*)d_in[3];
  const float* bpk = (const float*)d_in[4];
  const float* Wo  = (const float*)d_in[5];
  const float* bo  = (const float*)d_in[6];

  // workspace layout (bytes) — identical to rounds 3-7 verified layout.
  const size_t OFF_WR   = 0;            // Wr   (32,256,4096) bf16   67,108,864
  const size_t OFF_XBF  = 67108864;     // xbf  (16384,1024)  bf16   33,554,432
  const size_t OFF_WQK  = 100663296;    // Wqk  (2048,1024)   bf16    4,194,304
  const size_t OFF_KPTP = 67108864;     // KpTp (4,1056,4096) bf16   34,603,008
  const size_t OFF_KCBF = 67108864;     // Kcbf (4,256,1024)  bf16    2,097,152
  const size_t OFF_KCT  = 69206016;     // KcT  (4,1024,256)  bf16    2,097,152
  const size_t OFF_WOBF = 101711872;    // Wobf (1024,1024)   bf16    2,097,152
  const size_t OFF_QBF  = 104857600;    // Qbf  (4,4096,1024) bf16   33,554,432
  const size_t OFF_KP   = 138412032;    // Kp/AO(4,4096,1024) bf16   33,554,432
  const size_t OFF_KC   = 171966464;    // Kc   (4,256,1024)  f32     4,194,304
  const size_t NEED     = 176160768;
  if (ws_size < NEED) return;

  char* ws = (char*)d_ws;
  short* Wr   = (short*)(ws + OFF_WR);
  short* xbf  = (short*)(ws + OFF_XBF);
  short* Wqk  = (short*)(ws + OFF_WQK);
  short* KpTp = (short*)(ws + OFF_KPTP);
  short* Kcbf = (short*)(ws + OFF_KCBF);
  short* KcT  = (short*)(ws + OFF_KCT);
  short* Wobf = (short*)(ws + OFF_WOBF);
  short* Qbf  = (short*)(ws + OFF_QBF);
  short* Kp   = (short*)(ws + OFF_KP);
  float* Kc   = (float*)(ws + OFF_KC);
  short* AO   = Kp;
  float* Ppart = (float*)d_out;   // 16 x 4 MB partials; dead before k_gemm_out
  float* outp = (float*)d_out;

  k_cvt<<<dim3(8192), dim3(256), 0, stream>>>(x, xbf, 16777216 / 8);
  k_cvt<<<dim3(512),  dim3(256), 0, stream>>>(Wq, Wqk, 1048576 / 8);
  k_cvt<<<dim3(512),  dim3(256), 0, stream>>>(Wk, Wqk + 1048576, 1048576 / 8);
  k_reorder_wpk<<<dim3(16384), dim3(256), 0, stream>>>(Wpk, Wr);
  k_gemm_qk_v4<<<dim3(64, 16), dim3(256), 0, stream>>>(xbf, Wqk, Qbf, Kp);
  k_transpose_pad<<<dim3(64, 16, 4), dim3(256), 0, stream>>>(Kp, KpTp);
  k_cvt<<<dim3(512), dim3(256), 0, stream>>>(Wo, Wobf, 1048576 / 8);
  k_zero_pad<<<dim3(256), dim3(256), 0, stream>>>(KpTp);
  k_conv_v7<<<dim3(512), dim3(512), 0, stream>>>(Wr, KpTp, Ppart);
  k_reduce_kc<<<dim3(1024), dim3(256), 0, stream>>>(Ppart, bpk, Kc);
  k_kc_post<<<dim3(4, 16, 4), dim3(256), 0, stream>>>(Kc, Kcbf, KcT);
  k_attn<<<dim3(32, 8, 4), dim3(256), 0, stream>>>(Qbf, Kcbf, KcT, AO);
  k_gemm_out_v3<<<dim3(128, 8), dim3(256), 0, stream>>>(AO, Wobf, bo, outp);
}

// Round 9
// 598.457 us; speedup vs baseline: 1.4009x; 1.4009x over previous
//
#include <hip/hip_runtime.h>

// ---------------------------------------------------------------------------
// ConvLinformerSelfAttention (MI355X/gfx950) — bf16 MFMA pipeline, round 9.
// conv: v5 revert (proven 236us, 55% MfmaUtil, 16 waves/CU).
// qk: v4 (256x128 block, 64x128 wave-tiles). out: NEW v4 (same structure).
// ---------------------------------------------------------------------------

typedef short v8s __attribute__((ext_vector_type(8)));   // 8 x bf16 bits
typedef float v4f __attribute__((ext_vector_type(4)));

#define MFMA16(a, b, c) __builtin_amdgcn_mfma_f32_16x16x32_bf16((a), (b), (c), 0, 0, 0)
#define WAITV(N) asm volatile("s_waitcnt vmcnt(" #N ")" ::: "memory")
#define SBAR() __builtin_amdgcn_s_barrier()

__device__ __forceinline__ unsigned short f2bf(float f) {
  unsigned int u = __float_as_uint(f);
  u += 0x7fffu + ((u >> 16) & 1u);   // RNE
  return (unsigned short)(u >> 16);
}

__device__ __forceinline__ v8s cvt8(float4 a, float4 b) {
  v8s v;
  v[0] = (short)f2bf(a.x); v[1] = (short)f2bf(a.y);
  v[2] = (short)f2bf(a.z); v[3] = (short)f2bf(a.w);
  v[4] = (short)f2bf(b.x); v[5] = (short)f2bf(b.y);
  v[6] = (short)f2bf(b.z); v[7] = (short)f2bf(b.w);
  return v;
}

// async global->LDS, 16B per lane; LDS dest = uniform base + lane*16.
__device__ __forceinline__ void gld16(void* lds, const void* g) {
  __builtin_amdgcn_global_load_lds(
      (const __attribute__((address_space(1))) void*)g,
      (__attribute__((address_space(3))) void*)lds, 16, 0, 0);
}

// Fragment pointer into a swizzled [rows][32] bf16 LDS tile.
// Storage: LDS(row, seg') holds global seg = seg' ^ ((row>>1)&3).
__device__ __forceinline__ const v8s* frag_ptr(const short* base, int row, int g) {
  return (const v8s*)(base + row * 32 + (((g ^ (row >> 1)) & 3) << 3));
}

// --------------------------------------------------------------- cvt f32->bf16
__global__ __launch_bounds__(256) void k_cvt(const float* __restrict__ src,
                                             short* __restrict__ dst, int n8) {
  const int i = blockIdx.x * 256 + threadIdx.x;
  if (i >= n8) return;
  const float4* s = (const float4*)src;
  ((v8s*)dst)[i] = cvt8(s[2 * i], s[2 * i + 1]);
}

// --------------------------------------------------------------- reorder Wpk
__global__ __launch_bounds__(256) void k_reorder_wpk(const float* __restrict__ Wpk,
                                                     short* __restrict__ Wr) {
  __shared__ short T[64][40];
  const int k  = blockIdx.x >> 6;
  const int n0 = (blockIdx.x & 63) << 6;
  const int tid = threadIdx.x;
  {
    const int i = tid >> 2, t0 = (tid & 3) << 3;
    const float* p = Wpk + ((size_t)k * 4096 + n0 + i) * 32 + t0;
    float4 a = *(const float4*)p, b = *(const float4*)(p + 4);
    *(v8s*)&T[i][t0] = cvt8(a, b);
  }
  __syncthreads();
  {
    const int t = tid >> 3, j0 = (tid & 7) << 3;
    v8s o;
#pragma unroll
    for (int q = 0; q < 8; ++q) o[q] = T[j0 + q][t];
    *(v8s*)(Wr + ((size_t)t * 256 + k) * 4096 + n0 + j0) = o;
  }
}

// --------------------------------------------------------------- zero pads
__global__ __launch_bounds__(256) void k_zero_pad(short* __restrict__ KpTp) {
  const int idx = blockIdx.x * 256 + threadIdx.x;   // < 65536
  const int ridx = idx >> 9, col8 = idx & 511;
  const int b = ridx >> 5, rr = ridx & 31;
  const int row = (rr < 15) ? rr : 1039 + (rr - 15);
  v8s z = {0, 0, 0, 0, 0, 0, 0, 0};
  *(v8s*)(KpTp + ((size_t)b * 1056 + row) * 4096 + col8 * 8) = z;
}

// --------------------------------------------------------------- QK GEMM v4
// [Q|Kp](16384x2048) = xbf @ Wqk^T. grid (64,16): block 256(M)x128(N),
// 4 waves of 64x128, depth-1 counted vmcnt.
__global__ __launch_bounds__(256, 2) void k_gemm_qk_v4(const short* __restrict__ xbf,
                                                       const short* __restrict__ Wqk,
                                                       short* __restrict__ Qbf,
                                                       short* __restrict__ Kp) {
  __shared__ short As[2][256][32];
  __shared__ short Bs[2][128][32];
  const int tid = threadIdx.x, lane = tid & 63, w = tid >> 6;
  const int m0 = blockIdx.x * 256, j0 = blockIdx.y * 128;
  const int wm = w * 64;
  const int l15 = lane & 15, g = lane >> 4;
  const int lr = lane >> 2, lseg = lane & 3;

  v4f acc[4][8];
#pragma unroll
  for (int i = 0; i < 4; ++i)
#pragma unroll
    for (int j = 0; j < 8; ++j) acc[i][j] = (v4f)0.0f;

  auto stage = [&](int buf, int k0) {
#pragma unroll
    for (int q = 0; q < 4; ++q) {                 // A: 256 rows, 4 rounds
      const int rblk = q * 64 + w * 16, r = rblk + lr;
      const int co = ((lseg ^ (r >> 1)) & 3) << 3;
      gld16(&As[buf][rblk][0], xbf + (size_t)(m0 + r) * 1024 + k0 + co);
    }
#pragma unroll
    for (int q = 0; q < 2; ++q) {                 // B: 128 rows, 2 rounds
      const int rblk = q * 64 + w * 16, r = rblk + lr;
      const int co = ((lseg ^ (r >> 1)) & 3) << 3;
      gld16(&Bs[buf][rblk][0], Wqk + (size_t)(j0 + r) * 1024 + k0 + co);
    }
  };

  stage(0, 0);
#pragma unroll 1
  for (int p = 0, buf = 0; p < 32; ++p, buf ^= 1) {
    if (p + 1 < 32) stage(buf ^ 1, (p + 1) * 32);
    if (p < 31) { WAITV(6); } else { WAITV(0); }
    SBAR();
    v8s af[4];
#pragma unroll
    for (int mi = 0; mi < 4; ++mi)
      af[mi] = *frag_ptr(&As[buf][0][0], wm + mi * 16 + l15, g);
    __builtin_amdgcn_s_setprio(1);
#pragma unroll
    for (int nh = 0; nh < 2; ++nh) {
      v8s bq[4];
#pragma unroll
      for (int nj = 0; nj < 4; ++nj)
        bq[nj] = *frag_ptr(&Bs[buf][0][0], nh * 64 + nj * 16 + l15, g);
#pragma unroll
      for (int nj = 0; nj < 4; ++nj)
#pragma unroll
        for (int mi = 0; mi < 4; ++mi)
          acc[mi][nh * 4 + nj] = MFMA16(af[mi], bq[nj], acc[mi][nh * 4 + nj]);
    }
    __builtin_amdgcn_s_setprio(0);
    SBAR();
  }
  const int rbase = g * 4;
#pragma unroll
  for (int mi = 0; mi < 4; ++mi)
#pragma unroll
    for (int nf = 0; nf < 8; ++nf) {
      const int col = j0 + nf * 16 + l15;
      short* dst = (col < 1024) ? Qbf : Kp;
      const int cj = (col < 1024) ? col : col - 1024;
#pragma unroll
      for (int r = 0; r < 4; ++r) {
        const int row = m0 + wm + mi * 16 + rbase + r;
        dst[(size_t)row * 1024 + cj] = (short)f2bf(acc[mi][nf][r]);
      }
    }
}

// --------------------------------------------------------------- transpose+pad
__global__ __launch_bounds__(256) void k_transpose_pad(const short* __restrict__ src,
                                                       short* __restrict__ dst) {
  __shared__ short T[64][72];
  const int r0 = blockIdx.x * 64, c0 = blockIdx.y * 64, b = blockIdx.z;
  const int tid = threadIdx.x;
  {
    const int i = tid >> 2, q = (tid & 3) << 4;
    const short* ps = src + ((size_t)b * 4096 + r0 + i) * 1024 + c0 + q;
    *(v8s*)&T[i][q]     = *(const v8s*)ps;
    *(v8s*)&T[i][q + 8] = *(const v8s*)(ps + 8);
  }
  __syncthreads();
  {
    const int j = tid >> 2, p = (tid & 3) << 4;
    v8s o0, o1;
#pragma unroll
    for (int t = 0; t < 8; ++t) o0[t] = T[p + t][j];
#pragma unroll
    for (int t = 0; t < 8; ++t) o1[t] = T[p + 8 + t][j];
    short* pd = dst + ((size_t)b * 1056 + 15 + c0 + j) * 4096 + r0 + p;
    *(v8s*)pd = o0;
    *(v8s*)(pd + 8) = o1;
  }
}

// --------------------------------------------------------------- conv GEMM v5
// P[ns][b][kch 256][d-window 128] = sum_{t,n in ns-chunk} Wr x shifted(KpTp)
// grid 512 = ns(16) x b(4) x nt(8); 512 thr, 8 waves (4M x 2N); 2 blocks/CU.
// (round-6 verified: 236us, MfmaUtil 55%)
__global__ __launch_bounds__(512, 4) void k_conv_v5(const short* __restrict__ Wr,
                                                    const short* __restrict__ KpTp,
                                                    float* __restrict__ Pq) {
  __shared__ short A[3][256][32];    // 48 KB: t-plane A tiles, triple buffer
  __shared__ short Kt[2][160][32];   // 20 KB: halo'd KpTp (159 used rows), dbuf
  const int bid = blockIdx.x;
  // 32 blocks sharing one A-stream (same ns) share bid%8 -> same XCD L2.
  const int ns = (bid & 7) | (((bid >> 8) & 1) << 3);
  const int j  = (bid >> 3) & 31;
  const int b = j >> 3, nt = j & 7;
  const int D0 = nt * 128;
  const int nbase = ns * 256;
  const int tid = threadIdx.x, lane = tid & 63, w = tid >> 6;
  const int wm = (w >> 1) * 64, wn = (w & 1) * 64;
  const int l15 = lane & 15, g = lane >> 4;
  const int lr = lane >> 2, lseg = lane & 3;
  const short* KpTb = KpTp + (size_t)b * 1056 * 4096;

  v4f acc[4][4];
#pragma unroll
  for (int mi = 0; mi < 4; ++mi)
#pragma unroll
    for (int ni = 0; ni < 4; ++ni) acc[mi][ni] = (v4f)0.0f;

  // stage one 128-row round of the A tile for step s2 (1 gld16/lane/round).
  auto stageA = [&](int buf, int s2, int q) {
    const int t2 = s2 & 31, c2 = s2 >> 5;
    const int rblk = q * 128 + w * 16;
    const int row = rblk + lr;
    const int sg = ((lseg ^ (row >> 1)) & 3) << 3;
    gld16(&A[buf][rblk][0],
          Wr + ((size_t)t2 * 256 + row) * 4096 + nbase + c2 * 32 + sg);
  };
  // Kt: 159 used rows. q=0: rows 0..127 (all waves); q=1: rows 128..159
  // (waves 0,1 only; row 159 clamped junk).
  auto stageKt = [&](int buf, int c1, int q) {
    const int rblk = q * 128 + w * 16;
    const int row = rblk + lr;
    const int srow = row < 159 ? row : 158;
    const int sg = ((lseg ^ (row >> 1)) & 3) << 3;
    gld16(&Kt[buf][rblk][0],
          KpTb + (size_t)(D0 + srow) * 4096 + nbase + c1 * 32 + sg);
  };

  // prologue: A(0), Kt(0), A(1); drain all but A(1)'s 2 rounds.
  stageA(0, 0, 0); stageA(0, 0, 1);
  stageKt(0, 0, 0);
  if (w < 2) stageKt(0, 0, 1);
  stageA(1, 1, 0); stageA(1, 1, 1);
  WAITV(2);
  SBAR();

  // Hazards per step s (buffers cycle s%3): RAW on A[s%3] covered by prev
  // step's WAITV (drains A(s)) + SBAR; WAR on gld16 target (s+2)%3=(s-1)%3
  // covered by prev step's end barrier (all waves' ds_reads of s-1 done).
  int ab = 0, pab = 2;
#pragma unroll 1
  for (int s = 0; s < 256; ++s) {
    const int t = s & 31, c = s >> 5;
    const short* Abp = &A[ab][0][0];
    const short* Ktp = &Kt[c & 1][0][0];
    v8s aq[4], bq[4];
#pragma unroll
    for (int mi = 0; mi < 4; ++mi)
      aq[mi] = *frag_ptr(Abp, wm + mi * 16 + l15, g);
#pragma unroll
    for (int ni = 0; ni < 4; ++ni)
      bq[ni] = *frag_ptr(Ktp, wn + ni * 16 + l15 + t, g);
    if (s + 2 < 256) { stageA(pab, s + 2, 0); stageA(pab, s + 2, 1); }
    const bool kt0 = (t == 26) && (c < 7);
    const bool kt1 = (t == 27) && (c < 7);
    if (kt0) stageKt((c + 1) & 1, c + 1, 0);
    if (kt1 && w < 2) stageKt((c + 1) & 1, c + 1, 1);
    __builtin_amdgcn_s_setprio(1);
#pragma unroll
    for (int ni = 0; ni < 4; ++ni)
#pragma unroll
      for (int mi = 0; mi < 4; ++mi)
        acc[mi][ni] = MFMA16(aq[mi], bq[ni], acc[mi][ni]);
    __builtin_amdgcn_s_setprio(0);
    // counted wait: drain A(s+1) and older (incl. old Kt); keep A(s+2)
    // (+ this step's Kt round) in flight. In-order vmcnt retirement.
    if (s < 254) {
      if (kt0 || kt1) { WAITV(3); } else { WAITV(2); }
    } else if (s == 254) {
      WAITV(0);
    }
    SBAR();
    pab = ab; ab = (ab == 2) ? 0 : ab + 1;
  }

  float* Pp = Pq + (size_t)(ns * 4 + b) * 262144;  // [256][1024] window
#pragma unroll
  for (int mi = 0; mi < 4; ++mi)
#pragma unroll
    for (int ni = 0; ni < 4; ++ni) {
      const int col = D0 + wn + ni * 16 + l15;
#pragma unroll
      for (int r = 0; r < 4; ++r)
        Pp[(size_t)(wm + mi * 16 + g * 4 + r) * 1024 + col] = acc[mi][ni][r];
    }
}

// --------------------------------------------------------------- reduce Kc
// Kc[i] = bpk[k] + sum_{ns<16} P[ns][i], i over (4,256,1024). grid 1024x256.
__global__ __launch_bounds__(256) void k_reduce_kc(const float* __restrict__ P,
                                                   const float* __restrict__ bpk,
                                                   float* __restrict__ Kc) {
  const int i = (blockIdx.x * 256 + threadIdx.x) * 4;  // < 4*256*1024
  const float bias = bpk[(i >> 10) & 255];
  float4 s; s.x = bias; s.y = bias; s.z = bias; s.w = bias;
#pragma unroll
  for (int ns = 0; ns < 16; ++ns) {
    float4 v = *(const float4*)(P + (size_t)ns * 1048576 + i);
    s.x += v.x; s.y += v.y; s.z += v.z; s.w += v.w;
  }
  *(float4*)(Kc + i) = s;
}

// --------------------------------------------------------------- Kc post
__global__ __launch_bounds__(256) void k_kc_post(const float* __restrict__ Kc,
                                                 short* __restrict__ Kcbf,
                                                 short* __restrict__ KcT) {
  __shared__ short T[64][72];
  const int k0 = blockIdx.x * 64, d0 = blockIdx.y * 64, b = blockIdx.z;
  const int tid = threadIdx.x;
  {
    const int i = tid >> 2, q = (tid & 3) << 4;
    const float* ps = Kc + (size_t)(b * 256 + k0 + i) * 1024 + d0 + q;
    float4 f0 = *(const float4*)ps,       f1 = *(const float4*)(ps + 4);
    float4 f2 = *(const float4*)(ps + 8), f3 = *(const float4*)(ps + 12);
    v8s v0 = cvt8(f0, f1), v1 = cvt8(f2, f3);
    *(v8s*)&T[i][q] = v0;
    *(v8s*)&T[i][q + 8] = v1;
    short* pc = Kcbf + (size_t)(b * 256 + k0 + i) * 1024 + d0 + q;
    *(v8s*)pc = v0;
    *(v8s*)(pc + 8) = v1;
  }
  __syncthreads();
  {
    const int j = tid >> 2, p = (tid & 3) << 4;
    v8s o0, o1;
#pragma unroll
    for (int t = 0; t < 8; ++t) o0[t] = T[p + t][j];
#pragma unroll
    for (int t = 0; t < 8; ++t) o1[t] = T[p + 8 + t][j];
    short* pd = KcT + (size_t)(b * 1024 + d0 + j) * 256 + k0 + p;
    *(v8s*)pd = o0;
    *(v8s*)(pd + 8) = o1;
  }
}

// --------------------------------------------------------------- attention
__global__ __launch_bounds__(256) void k_attn(const short* __restrict__ Qbf,
                                              const short* __restrict__ Kcbf,
                                              const short* __restrict__ KcT,
                                              short* __restrict__ AO) {
  __shared__ short P[4][16][264];
  const int nt = blockIdx.x, h = blockIdx.y, b = blockIdx.z;
  const int tid = threadIdx.x, lane = tid & 63, w = tid >> 6;
  const int l15 = lane & 15, lg4 = (lane >> 4) * 4, lg8 = (lane >> 4) * 8;
  const float scale = 0.08838834764831845f;
  const size_t qb  = (size_t)b * 4096 * 1024 + (size_t)h * 128;
  const size_t kb  = (size_t)b * 256 * 1024 + (size_t)h * 128;
  const size_t vtb = ((size_t)b * 1024 + (size_t)h * 128) * 256;
  short (*Pw)[264] = P[w];
  const int n_wave = nt * 128 + w * 32;

#pragma unroll 1
  for (int half = 0; half < 2; ++half) {
    const int nbase = n_wave + half * 16;
    v8s aq[4];
#pragma unroll
    for (int kt = 0; kt < 4; ++kt)
      aq[kt] = *(const v8s*)(Qbf + qb + (size_t)(nbase + l15) * 1024 + kt * 32 + lg8);

    v4f dacc[16];
#pragma unroll
    for (int ct = 0; ct < 16; ++ct) dacc[ct] = (v4f)0.0f;
#pragma unroll 1
    for (int kt = 0; kt < 4; ++kt) {
#pragma unroll
      for (int ct = 0; ct < 16; ++ct) {
        v8s bk = *(const v8s*)(Kcbf + kb + (size_t)(ct * 16 + l15) * 1024 + kt * 32 + lg8);
        dacc[ct] = MFMA16(aq[kt], bk, dacc[ct]);
      }
    }
#pragma unroll
    for (int ct = 0; ct < 16; ++ct) dacc[ct] = dacc[ct] * scale;
    v4f m4 = dacc[0];
#pragma unroll
    for (int ct = 1; ct < 16; ++ct)
#pragma unroll
      for (int r = 0; r < 4; ++r) m4[r] = fmaxf(m4[r], dacc[ct][r]);
#pragma unroll
    for (int off = 1; off < 16; off <<= 1)
#pragma unroll
      for (int r = 0; r < 4; ++r) m4[r] = fmaxf(m4[r], __shfl_xor(m4[r], off, 64));
    v4f ssum = (v4f)0.0f;
#pragma unroll
    for (int ct = 0; ct < 16; ++ct)
#pragma unroll
      for (int r = 0; r < 4; ++r) {
        const float e = __expf(dacc[ct][r] - m4[r]);
        ssum[r] += e;
        Pw[lg4 + r][ct * 16 + l15] = (short)f2bf(e);
      }
#pragma unroll
    for (int off = 1; off < 16; off <<= 1)
#pragma unroll
      for (int r = 0; r < 4; ++r) ssum[r] += __shfl_xor(ssum[r], off, 64);
    __syncthreads();

    v4f oacc[8];
#pragma unroll
    for (int ct = 0; ct < 8; ++ct) oacc[ct] = (v4f)0.0f;
#pragma unroll 1
    for (int kt2 = 0; kt2 < 8; ++kt2) {
      v8s pa = *(const v8s*)&Pw[l15][kt2 * 32 + lg8];
#pragma unroll
      for (int ct = 0; ct < 8; ++ct) {
        v8s bv = *(const v8s*)(KcT + vtb + (size_t)(ct * 16 + l15) * 256 + kt2 * 32 + lg8);
        oacc[ct] = MFMA16(pa, bv, oacc[ct]);
      }
    }
    v4f inv;
#pragma unroll
    for (int r = 0; r < 4; ++r) inv[r] = 1.0f / ssum[r];
#pragma unroll
    for (int ct = 0; ct < 8; ++ct)
#pragma unroll
      for (int r = 0; r < 4; ++r)
        AO[qb + (size_t)(nbase + lg4 + r) * 1024 + ct * 16 + l15] =
            (short)f2bf(oacc[ct][r] * inv[r]);
    __syncthreads();
  }
}

// --------------------------------------------------------------- out GEMM v4
// out(16384x1024) f32 = AO @ Wobf^T + bo. grid (64,8): block 256(M)x128(N),
// 4 waves of 64x128, depth-1 counted vmcnt (qk_v4 structure).
__global__ __launch_bounds__(256, 2) void k_gemm_out_v4(const short* __restrict__ AO,
                                                        const short* __restrict__ Wobf,
                                                        const float* __restrict__ bo,
                                                        float* __restrict__ out) {
  __shared__ short As[2][256][32];
  __shared__ short Bs[2][128][32];
  const int tid = threadIdx.x, lane = tid & 63, w = tid >> 6;
  const int m0 = blockIdx.x * 256, j0 = blockIdx.y * 128;
  const int wm = w * 64;
  const int l15 = lane & 15, g = lane >> 4;
  const int lr = lane >> 2, lseg = lane & 3;

  v4f acc[4][8];
#pragma unroll
  for (int i = 0; i < 4; ++i)
#pragma unroll
    for (int j = 0; j < 8; ++j) acc[i][j] = (v4f)0.0f;

  auto stage = [&](int buf, int k0) {
#pragma unroll
    for (int q = 0; q < 4; ++q) {                 // A: 256 rows, 4 rounds
      const int rblk = q * 64 + w * 16, r = rblk + lr;
      const int co = ((lseg ^ (r >> 1)) & 3) << 3;
      gld16(&As[buf][rblk][0], AO + (size_t)(m0 + r) * 1024 + k0 + co);
    }
#pragma unroll
    for (int q = 0; q < 2; ++q) {                 // B: 128 rows, 2 rounds
      const int rblk = q * 64 + w * 16, r = rblk + lr;
      const int co = ((lseg ^ (r >> 1)) & 3) << 3;
      gld16(&Bs[buf][rblk][0], Wobf + (size_t)(j0 + r) * 1024 + k0 + co);
    }
  };

  stage(0, 0);
#pragma unroll 1
  for (int p = 0, buf = 0; p < 32; ++p, buf ^= 1) {
    if (p + 1 < 32) stage(buf ^ 1, (p + 1) * 32);
    if (p < 31) { WAITV(6); } else { WAITV(0); }
    SBAR();
    v8s af[4];
#pragma unroll
    for (int mi = 0; mi < 4; ++mi)
      af[mi] = *frag_ptr(&As[buf][0][0], wm + mi * 16 + l15, g);
    __builtin_amdgcn_s_setprio(1);
#pragma unroll
    for (int nh = 0; nh < 2; ++nh) {
      v8s bq[4];
#pragma unroll
      for (int nj = 0; nj < 4; ++nj)
        bq[nj] = *frag_ptr(&Bs[buf][0][0], nh * 64 + nj * 16 + l15, g);
#pragma unroll
      for (int nj = 0; nj < 4; ++nj)
#pragma unroll
        for (int mi = 0; mi < 4; ++mi)
          acc[mi][nh * 4 + nj] = MFMA16(af[mi], bq[nj], acc[mi][nh * 4 + nj]);
    }
    __builtin_amdgcn_s_setprio(0);
    SBAR();
  }
  const int rbase = g * 4;
#pragma unroll
  for (int mi = 0; mi < 4; ++mi)
#pragma unroll
    for (int nf = 0; nf < 8; ++nf) {
      const int col = j0 + nf * 16 + l15;
      const float bias = bo[col];
#pragma unroll
      for (int r = 0; r < 4; ++r) {
        const int row = m0 + wm + mi * 16 + rbase + r;
        out[(size_t)row * 1024 + col] = acc[mi][nf][r] + bias;
      }
    }
}

// ---------------------------------------------------------------------------
extern "C" void kernel_launch(void* const* d_in, const int* in_sizes, int n_in,
                              void* d_out, int out_size, void* d_ws, size_t ws_size,
                              hipStream_t stream) {
  const float* x   = (const float*)d_in[0];
  const float* Wq  = (const float*)d_in[1];
  const float* Wk  = (const float*)d_in[2];
  const float* Wpk = (const float*)d_in[3];
  const float* bpk = (const float*)d_in[4];
  const float* Wo  = (const float*)d_in[5];
  const float* bo  = (const float*)d_in[6];

  // workspace layout (bytes) — identical to rounds 3-8 verified layout.
  const size_t OFF_WR   = 0;            // Wr   (32,256,4096) bf16   67,108,864
  const size_t OFF_XBF  = 67108864;     // xbf  (16384,1024)  bf16   33,554,432
  const size_t OFF_WQK  = 100663296;    // Wqk  (2048,1024)   bf16    4,194,304
  const size_t OFF_KPTP = 67108864;     // KpTp (4,1056,4096) bf16   34,603,008
  const size_t OFF_KCBF = 67108864;     // Kcbf (4,256,1024)  bf16    2,097,152
  const size_t OFF_KCT  = 69206016;     // KcT  (4,1024,256)  bf16    2,097,152
  const size_t OFF_WOBF = 101711872;    // Wobf (1024,1024)   bf16    2,097,152
  const size_t OFF_QBF  = 104857600;    // Qbf  (4,4096,1024) bf16   33,554,432
  const size_t OFF_KP   = 138412032;    // Kp/AO(4,4096,1024) bf16   33,554,432
  const size_t OFF_KC   = 171966464;    // Kc   (4,256,1024)  f32     4,194,304
  const size_t NEED     = 176160768;
  if (ws_size < NEED) return;

  char* ws = (char*)d_ws;
  short* Wr   = (short*)(ws + OFF_WR);
  short* xbf  = (short*)(ws + OFF_XBF);
  short* Wqk  = (short*)(ws + OFF_WQK);
  short* KpTp = (short*)(ws + OFF_KPTP);
  short* Kcbf = (short*)(ws + OFF_KCBF);
  short* KcT  = (short*)(ws + OFF_KCT);
  short* Wobf = (short*)(ws + OFF_WOBF);
  short* Qbf  = (short*)(ws + OFF_QBF);
  short* Kp   = (short*)(ws + OFF_KP);
  float* Kc   = (float*)(ws + OFF_KC);
  short* AO   = Kp;
  float* Ppart = (float*)d_out;   // 16 x 4 MB partials; dead before k_gemm_out
  float* outp = (float*)d_out;

  k_cvt<<<dim3(8192), dim3(256), 0, stream>>>(x, xbf, 16777216 / 8);
  k_cvt<<<dim3(512),  dim3(256), 0, stream>>>(Wq, Wqk, 1048576 / 8);
  k_cvt<<<dim3(512),  dim3(256), 0, stream>>>(Wk, Wqk + 1048576, 1048576 / 8);
  k_reorder_wpk<<<dim3(16384), dim3(256), 0, stream>>>(Wpk, Wr);
  k_gemm_qk_v4<<<dim3(64, 16), dim3(256), 0, stream>>>(xbf, Wqk, Qbf, Kp);
  k_transpose_pad<<<dim3(64, 16, 4), dim3(256), 0, stream>>>(Kp, KpTp);
  k_cvt<<<dim3(512), dim3(256), 0, stream>>>(Wo, Wobf, 1048576 / 8);
  k_zero_pad<<<dim3(256), dim3(256), 0, stream>>>(KpTp);
  k_conv_v5<<<dim3(512), dim3(512), 0, stream>>>(Wr, KpTp, Ppart);
  k_reduce_kc<<<dim3(1024), dim3(256), 0, stream>>>(Ppart, bpk, Kc);
  k_kc_post<<<dim3(4, 16, 4), dim3(256), 0, stream>>>(Kc, Kcbf, KcT);
  k_attn<<<dim3(32, 8, 4), dim3(256), 0, stream>>>(Qbf, Kcbf, KcT, AO);
  k_gemm_out_v4<<<dim3(64, 8), dim3(256), 0, stream>>>(AO, Wobf, bo, outp);
}